// Round 3
// baseline (425.696 us; speedup 1.0000x reference)
//
#include <hip/hip_runtime.h>
#include <hip/hip_bf16.h>

#define NB   64
#define NC   1024
#define NQ   128
#define DIMD 512
#define BK   64
#define NKC  (DIMD / BK)   // 8 K-chunks
#define TM   128           // rows per context tile
#define NTILE (NC / TM)    // 8 tiles

using short8  = __attribute__((ext_vector_type(8))) short;
using short4v = __attribute__((ext_vector_type(4))) short;
using f32x4   = __attribute__((ext_vector_type(4))) float;
typedef __fp16 half2v __attribute__((ext_vector_type(2)));

__device__ inline float dot4(float4 a, float4 b) {
    return a.x * b.x + a.y * b.y + a.z * b.z + a.w * b.w;
}

__device__ inline short4v pack_bf16(float a, float b, float c, float d) {
    union { __hip_bfloat162 h[2]; short4v s; } p;
    p.h[0] = __float22bfloat162_rn(make_float2(a, b));
    p.h[1] = __float22bfloat162_rn(make_float2(c, d));
    return p.s;
}

// async global->LDS, 16 bytes per lane. LDS dest must be wave-uniform base
// (HW writes base + lane*16); global src is per-lane.
__device__ __forceinline__ void glds16(const void* g, void* l) {
    __builtin_amdgcn_global_load_lds(
        (const __attribute__((address_space(1))) unsigned int*)g,
        (__attribute__((address_space(3))) unsigned int*)l,
        16, 0, 0);
}

// ---------------------------------------------------------------------------
// K0 prep: one wave per row (ctx rows then qry rows).
//   ctx row: cm = bf16(ctx*wm) (16B/lane write), cw[row] = ctx . wc
//   qry row: qm = bf16(q),                        qw[row] = q . wq
// Pure streaming: reads 151 MB, writes 75 MB.
// ---------------------------------------------------------------------------
__global__ __launch_bounds__(256) void prep(
    const float* __restrict__ ctx, const float* __restrict__ qry,
    const float* __restrict__ w0,
    unsigned short* __restrict__ cm, unsigned short* __restrict__ qm,
    float* __restrict__ cw, float* __restrict__ qw)
{
    const int wv   = threadIdx.x >> 6;
    const int lane = threadIdx.x & 63;
    const int gid  = blockIdx.x * 4 + wv;
    const int d0   = lane * 8;
    const int NCTX = NB * NC;   // 65536 ctx rows; blocks >= 16384 are all-qry

    if (gid < NCTX) {
        const float* src = ctx + (size_t)gid * DIMD + d0;
        float4 v0 = *(const float4*)src;
        float4 v1 = *(const float4*)(src + 4);
        float4 m0 = *(const float4*)&w0[2 * DIMD + d0];
        float4 m1 = *(const float4*)&w0[2 * DIMD + d0 + 4];
        float4 c0 = *(const float4*)&w0[d0];
        float4 c1 = *(const float4*)&w0[d0 + 4];
        union { short4v h[2]; short8 v; } pk;
        pk.h[0] = pack_bf16(v0.x * m0.x, v0.y * m0.y, v0.z * m0.z, v0.w * m0.w);
        pk.h[1] = pack_bf16(v1.x * m1.x, v1.y * m1.y, v1.z * m1.z, v1.w * m1.w);
        *(short8*)(cm + (size_t)gid * DIMD + d0) = pk.v;
        float s = dot4(v0, c0) + dot4(v1, c1);
#pragma unroll
        for (int off = 1; off < 64; off <<= 1) s += __shfl_xor(s, off);
        if (lane == 0) cw[gid] = s;
    } else {
        const int j = gid - NCTX;
        const float* src = qry + (size_t)j * DIMD + d0;
        float4 v0 = *(const float4*)src;
        float4 v1 = *(const float4*)(src + 4);
        float4 q0 = *(const float4*)&w0[DIMD + d0];
        float4 q1 = *(const float4*)&w0[DIMD + d0 + 4];
        union { short4v h[2]; short8 v; } pk;
        pk.h[0] = pack_bf16(v0.x, v0.y, v0.z, v0.w);
        pk.h[1] = pack_bf16(v1.x, v1.y, v1.z, v1.w);
        *(short8*)(qm + (size_t)j * DIMD + d0) = pk.v;
        float s = dot4(v0, q0) + dot4(v1, q1);
#pragma unroll
        for (int off = 1; off < 64; off <<= 1) s += __shfl_xor(s, off);
        if (lane == 0) qw[j] = s;
    }
}

// ---------------------------------------------------------------------------
// K1 gemm_e: bf16 MFMA GEMM on pre-packed cm/qm, staged via global_load_lds
// (dwordx4, double-buffered). LDS linear [row][64]; bank-conflict-free frag
// reads via XOR chunk swizzle (source-side pre-swizzle + read-side XOR).
// Epilogue: E = exp(sim), spill fp16 col-major, Z from ROUNDED E.
// Grid (NB, NTILE), 256 thr = 4 waves (2x2 over 128x128).
// ---------------------------------------------------------------------------
__global__ __launch_bounds__(256) void gemm_e(
    const unsigned short* __restrict__ cm, const unsigned short* __restrict__ qm,
    const float* __restrict__ cw, const float* __restrict__ qw,
    float* __restrict__ stats, unsigned short* __restrict__ eh)
{
    __shared__ __attribute__((aligned(16))) unsigned short Abuf[2][TM][64]; // 32 KB
    __shared__ __attribute__((aligned(16))) unsigned short Bbuf[2][NQ][64]; // 32 KB
    __shared__ float cwL[TM], qwL[NQ];
    __shared__ float sL[2][NQ];

    const int tid  = threadIdx.x;
    const int b    = blockIdx.x;
    const int bt   = blockIdx.y;
    const int i0   = bt * TM;
    const int w    = tid >> 6;
    const int lane = tid & 63;
    const int wr   = w >> 1, wcg = w & 1;
    const int RB   = wr * 64, CB = wcg * 64;
    const int n16  = lane & 15, qd = lane >> 4;
    const int x7   = n16 & 7;          // rA&7 for all fragment rows

    if (tid < TM) cwL[tid] = cw[(size_t)b * NC + i0 + tid];
    else          qwL[tid - TM] = qw[(size_t)b * NQ + (tid - TM)];

    // staging addressing: wave w loads A rows [w*32, w*32+32) and same B rows,
    // 4 instr each (8 rows per instr). Lane: row-in-group rl, chunk cc; fetch
    // pre-swizzled global chunk cc^rl into linear LDS slot cc.
    const int rl  = lane >> 3;
    const int cc  = lane & 7;
    const int csw = cc ^ rl;
    const unsigned short* aSrc = cm + ((size_t)b * NC + i0 + w * 32 + rl) * DIMD + csw * 8;
    const unsigned short* bSrc = qm + ((size_t)b * NQ +      w * 32 + rl) * DIMD + csw * 8;

    f32x4 acc[4][4];
#pragma unroll
    for (int ri = 0; ri < 4; ri++)
#pragma unroll
        for (int ci = 0; ci < 4; ci++)
#pragma unroll
            for (int e = 0; e < 4; e++) acc[ri][ci][e] = 0.f;

    auto stage = [&](int buf, int kc) {
        const int kof = kc * 64;
#pragma unroll
        for (int i = 0; i < 4; i++) {
            glds16(aSrc + (size_t)i * 8 * DIMD + kof, (void*)&Abuf[buf][w * 32 + i * 8][0]);
            glds16(bSrc + (size_t)i * 8 * DIMD + kof, (void*)&Bbuf[buf][w * 32 + i * 8][0]);
        }
    };

    stage(0, 0);
    __syncthreads();

    for (int kc = 0; kc < NKC; kc++) {
        const int cur = kc & 1;
        if (kc + 1 < NKC) stage(cur ^ 1, kc + 1);
#pragma unroll
        for (int ks = 0; ks < 2; ks++) {
            short8 af[4], bfr[4];
#pragma unroll
            for (int ri = 0; ri < 4; ri++) {
                const int rA = RB + ri * 16 + n16;
                const int p  = (ks * 4 + qd) ^ x7;
                af[ri] = *(const short8*)&Abuf[cur][rA][p * 8];
            }
#pragma unroll
            for (int ci = 0; ci < 4; ci++) {
                const int rB = CB + ci * 16 + n16;
                const int p  = (ks * 4 + qd) ^ x7;
                bfr[ci] = *(const short8*)&Bbuf[cur][rB][p * 8];
            }
#pragma unroll
            for (int ri = 0; ri < 4; ri++)
#pragma unroll
                for (int ci = 0; ci < 4; ci++)
                    acc[ri][ci] = __builtin_amdgcn_mfma_f32_16x16x32_bf16(
                        af[ri], bfr[ci], acc[ri][ci], 0, 0, 0);
        }
        __syncthreads();   // drains vmcnt(0): next buffer staged; cur reads done
    }

    // Epilogue: v = acc + cw_i + qw_j; E = exp(v); spill fp16 E (col-major);
    // Z accumulated from the ROUNDED fp16 values for exact consistency.
    // C/D layout (16x16x32): col = lane&15, row = (lane>>4)*4 + reg
#pragma unroll
    for (int ci = 0; ci < 4; ci++) {
        const int col = CB + ci * 16 + n16;
        const float qwv = qwL[col];
        unsigned short* eCol = eh + ((size_t)(b * NTILE + bt) * NQ + col) * TM;
        float s = 0.f;
#pragma unroll
        for (int ri = 0; ri < 4; ri++) {
            const int rbase = RB + ri * 16 + qd * 4;
            float e0 = __expf(acc[ri][ci][0] + cwL[rbase + 0] + qwv);
            float e1 = __expf(acc[ri][ci][1] + cwL[rbase + 1] + qwv);
            float e2 = __expf(acc[ri][ci][2] + cwL[rbase + 2] + qwv);
            float e3 = __expf(acc[ri][ci][3] + cwL[rbase + 3] + qwv);
            half2v h01 = __builtin_amdgcn_cvt_pkrtz(e0, e1);
            half2v h23 = __builtin_amdgcn_cvt_pkrtz(e2, e3);
            s += (float)h01[0] + (float)h01[1] + (float)h23[0] + (float)h23[1];
            uint2 pk;
            pk.x = __builtin_bit_cast(unsigned, h01);
            pk.y = __builtin_bit_cast(unsigned, h23);
            *(uint2*)&eCol[rbase] = pk;
        }
        s += __shfl_xor(s, 16);
        s += __shfl_xor(s, 32);
        if (qd == 0) sL[wr][col] = s;
    }
    __syncthreads();
    if (tid < NQ)
        stats[(size_t)(b * NTILE + bt) * NQ + tid] = sL[0][tid] + sL[1][tid];
}

// ---------------------------------------------------------------------------
// K2 rb2: iz[j] = 1/sum_tiles Z; r_i = sum_j E_ij*iz_j (fp16 E, no expf);
// bpart[d] = sum_i r_i c_i[d] (float4/thread, split row-halves for ILP);
// plus this tile's 64-col slice of arow.
// Grid (NB, NTILE), block 256.
// ---------------------------------------------------------------------------
__global__ __launch_bounds__(256) void rb2(
    const float* __restrict__ ctx, const float* __restrict__ qry,
    const unsigned short* __restrict__ eh, const float* __restrict__ stats,
    float* __restrict__ bpart, float* __restrict__ arow)
{
    __shared__ __attribute__((aligned(16))) unsigned short eL[NQ * TM];
    __shared__ float izL[NQ];
    __shared__ float rpart[2][TM];
    __shared__ float rfin[TM];
    __shared__ float bH[2][DIMD];
    __shared__ float qL[4][64];

    const int tid = threadIdx.x;
    const int b = blockIdx.x, bt = blockIdx.y;
    const int i0 = bt * TM;

    if (tid < NQ) {
        float ssum = 0.f;
#pragma unroll
        for (int t8 = 0; t8 < NTILE; t8++)
            ssum += stats[(size_t)(b * NTILE + t8) * NQ + tid];
        izL[tid] = 1.0f / ssum;
    }
    const unsigned short* tileSrc = eh + (size_t)(b * NTILE + bt) * NQ * TM;
#pragma unroll
    for (int it = 0; it < 8; it++) {
        const int idx = (tid + it * 256) * 8;   // 8 ushorts = 16B per thread
        *(uint4*)&eL[idx] = *(const uint4*)&tileSrc[idx];
    }
    __syncthreads();

    const int i = tid & 127, jh = tid >> 7;
    float r = 0.f;
    for (int j2 = 0; j2 < 64; j2++) {
        const int j = jh * 64 + j2;
        __fp16 hv = __builtin_bit_cast(__fp16, eL[j * TM + i]);
        r += (float)hv * izL[j];
    }
    rpart[jh][i] = r;
    __syncthreads();
    if (tid < TM) rfin[tid] = rpart[0][tid] + rpart[1][tid];
    __syncthreads();

    // bpart: 128 threads per row-half, float4 per thread, unrolled for ILP
    const int dq = (tid & 127) * 4;
    const int rh = tid >> 7;
    f32x4 ba = {0.f, 0.f, 0.f, 0.f};
    const float* cb4 = ctx + ((size_t)b * NC + i0 + rh * 64) * DIMD + dq;
#pragma unroll 4
    for (int ii = 0; ii < 64; ii++) {
        float rv = rfin[rh * 64 + ii];
        f32x4 cv = *(const f32x4*)(cb4 + (size_t)ii * DIMD);
        ba += rv * cv;
    }
    *(f32x4*)&bH[rh][dq] = ba;
    __syncthreads();
    if (tid < 128) {
        const int d4 = tid * 4;
        f32x4 r0 = *(const f32x4*)&bH[0][d4];
        f32x4 r1 = *(const f32x4*)&bH[1][d4];
        f32x4 sum = r0 + r1;
        *(f32x4*)&bpart[(size_t)(b * NTILE + bt) * DIMD + d4] = sum;
    }

    // arow slice: this block computes arow[b][bt*64 .. bt*64+64)
    const int dcol = tid & 63, rgrp = tid >> 6;
    float qs = 0.f;
    const float* qb = qry + (size_t)b * NQ * DIMD + bt * 64 + dcol;
    for (int t = 0; t < 32; t++)
        qs += qb[(size_t)(t * 4 + rgrp) * DIMD];
    qL[rgrp][dcol] = qs;
    __syncthreads();
    if (tid < 64)
        arow[(size_t)b * DIMD + bt * 64 + tid] =
            qL[0][tid] + qL[1][tid] + qL[2][tid] + qL[3][tid];
}

// ---------------------------------------------------------------------------
// K3: reduce Brow partials + broadcast-write A and B (nontemporal).
// Grid (NB, 32), block 256.
// ---------------------------------------------------------------------------
__global__ void broadcast_out(const float* __restrict__ arow, const float* __restrict__ bpart,
                              float* __restrict__ out)
{
    const int b = blockIdx.x, ic = blockIdx.y;
    const int t = threadIdx.x;
    const int half = t >> 7;          // 0 -> A, 1 -> B (wave-uniform)
    const int l = t & 127;
    const int d0 = l * 4;
    f32x4 val;
    if (half == 0) {
        val = *(const f32x4*)&arow[(size_t)b * DIMD + d0];
    } else {
        val[0] = val[1] = val[2] = val[3] = 0.f;
        for (int t8 = 0; t8 < NTILE; t8++) {
            f32x4 v = *(const f32x4*)&bpart[(size_t)(b * NTILE + t8) * DIMD + d0];
            val[0] += v[0]; val[1] += v[1]; val[2] += v[2]; val[3] += v[3];
        }
    }
    size_t base = (size_t)half * ((size_t)NB * NC * DIMD)
                + ((size_t)b * NC + (size_t)ic * 32) * DIMD + d0;
    for (int i = 0; i < 32; i++)
        __builtin_nontemporal_store(val, (f32x4*)&out[base + (size_t)i * DIMD]);
}

extern "C" void kernel_launch(void* const* d_in, const int* in_sizes, int n_in,
                              void* d_out, int out_size, void* d_ws, size_t ws_size,
                              hipStream_t stream)
{
    const float* ctx = (const float*)d_in[0];  // (64,1024,512) f32
    const float* qry = (const float*)d_in[1];  // (64,128,512) f32
    const float* w0  = (const float*)d_in[2];  // (1536,) f32
    float* out = (float*)d_out;
    float* ws  = (float*)d_ws;

    unsigned short* cm = (unsigned short*)ws;                 // 33.5M ushorts (67 MB)
    unsigned short* qm = (unsigned short*)(ws + 16777216);    // 4.2M ushorts (8.4 MB)
    float* cw    = ws + 18874368;   // 65536 floats
    float* qw    = ws + 18939904;   // 8192
    float* stats = ws + 18948096;   // 65536
    float* arow  = ws + 19013632;   // 32768
    float* bpart = ws + 19046400;   // 262144
    unsigned short* eh = (unsigned short*)(ws + 19308544);    // 8.4M ushorts (16.8 MB)

    prep<<<dim3((NB * NC + NB * NQ) / 4), 256, 0, stream>>>(ctx, qry, w0, cm, qm, cw, qw);
    gemm_e<<<dim3(NB, NTILE), 256, 0, stream>>>(cm, qm, cw, qw, stats, eh);
    rb2<<<dim3(NB, NTILE), 256, 0, stream>>>(ctx, qry, eh, stats, bpart, arow);
    broadcast_out<<<dim3(NB, 32), 256, 0, stream>>>(arow, bpart, out);
}

// Round 4
// 414.000 us; speedup vs baseline: 1.0283x; 1.0283x over previous
//
#include <hip/hip_runtime.h>
#include <hip/hip_bf16.h>

#define NB   64
#define NC   1024
#define NQ   128
#define DIMD 512
#define BK   64
#define NKC  (DIMD / BK)   // 8 K-chunks
#define LDK  (BK + 8)      // 72 shorts per LDS row (pad; keeps 16B align)
#define TM   128           // rows per context tile
#define NTILE (NC / TM)    // 8 tiles

using short8  = __attribute__((ext_vector_type(8))) short;
using short4v = __attribute__((ext_vector_type(4))) short;
using f32x4   = __attribute__((ext_vector_type(4))) float;
typedef __fp16 half2v __attribute__((ext_vector_type(2)));

__device__ inline float dot4(float4 a, float4 b) {
    return a.x * b.x + a.y * b.y + a.z * b.z + a.w * b.w;
}

// ---------------------------------------------------------------------------
// K1: bf16 MFMA GEMM with fused transform. Linear grid 512, XCD-chunked
// swizzle: XCD x handles batches 8x..8x+7 (all tiles of a batch share L2).
// Staging is two-phase per K-chunk: (a) issue all 16 independent float4
// global loads into registers, (b) transform + ds_write. ~256B/thread in
// flight -> latency-covered. Epilogue: E = exp(sim), spill fp16 col-major,
// Z accumulated from ROUNDED E for exact consistency with K2.
// ---------------------------------------------------------------------------
__global__ __launch_bounds__(256) void gemm_stats(
    const float* __restrict__ ctx, const float* __restrict__ qry,
    const float* __restrict__ w0, float* __restrict__ stats,
    unsigned short* __restrict__ eh)
{
    __shared__ __attribute__((aligned(16))) short As[TM][LDK];  // bf16(c * wm)
    __shared__ __attribute__((aligned(16))) short Bs[NQ][LDK];  // bf16(q)
    __shared__ __attribute__((aligned(16))) float w0L[3 * DIMD];
    __shared__ float cwL[TM], qwL[NQ];
    __shared__ float sL[2][NQ];

    const int tid  = threadIdx.x;
    const int bid  = blockIdx.x;
    const int orig = (bid & 7) * 64 + (bid >> 3);   // XCD-chunked swizzle
    const int b    = orig >> 3;
    const int bt   = orig & 7;
    const int i0   = bt * TM;
    const int w    = tid >> 6;
    const int lane = tid & 63;
    const int wr   = w >> 1, wcg = w & 1;
    const int RB   = wr * 64, CB = wcg * 64;
    const int n16  = lane & 15, qd = lane >> 4;

    for (int idx = tid; idx < 3 * DIMD; idx += 256) w0L[idx] = w0[idx];

    f32x4 acc[4][4];
#pragma unroll
    for (int ri = 0; ri < 4; ri++)
#pragma unroll
        for (int ci = 0; ci < 4; ci++)
#pragma unroll
            for (int e = 0; e < 4; e++) acc[ri][ci][e] = 0.f;

    // staging: 16 lanes per row (coalesced 256B segments), 4 rows/inst,
    // 8 row-steps (u) cover the wave's 32 rows.
    const int col4  = n16 * 4;
    const int srow0 = w * 32 + qd;                 // row for u=0; +4 per u
    const float* cBase = ctx + ((size_t)(b * NC + i0 + srow0)) * DIMD + col4;
    const float* qBase = qry + ((size_t)(b * NQ + srow0)) * DIMD + col4;
    float cwp[8], qwp[8];
#pragma unroll
    for (int u = 0; u < 8; u++) { cwp[u] = 0.f; qwp[u] = 0.f; }

    for (int kc = 0; kc < NKC; kc++) {
        const int k0 = kc * BK;
        __syncthreads();   // prior MFMA done reading As/Bs (covers w0L on kc=0)
        float4 wcv = *(const float4*)&w0L[k0 + col4];
        float4 wqv = *(const float4*)&w0L[DIMD + k0 + col4];
        float4 wmv = *(const float4*)&w0L[2 * DIMD + k0 + col4];

        // phase A: issue all 16 independent loads
        float4 cv[8], qv[8];
#pragma unroll
        for (int u = 0; u < 8; u++) {
            cv[u] = *(const float4*)(cBase + k0 + (size_t)u * 4 * DIMD);
            qv[u] = *(const float4*)(qBase + k0 + (size_t)u * 4 * DIMD);
        }
        // phase B: transform + LDS write
#pragma unroll
        for (int u = 0; u < 8; u++) {
            const int row = w * 32 + u * 4 + qd;
            cwp[u] += dot4(cv[u], wcv);
            union { __hip_bfloat162 h[2]; short4v s; } pc;
            pc.h[0] = __float22bfloat162_rn(make_float2(cv[u].x * wmv.x, cv[u].y * wmv.y));
            pc.h[1] = __float22bfloat162_rn(make_float2(cv[u].z * wmv.z, cv[u].w * wmv.w));
            *(short4v*)&As[row][col4] = pc.s;

            qwp[u] += dot4(qv[u], wqv);
            union { __hip_bfloat162 h[2]; short4v s; } pq;
            pq.h[0] = __float22bfloat162_rn(make_float2(qv[u].x, qv[u].y));
            pq.h[1] = __float22bfloat162_rn(make_float2(qv[u].z, qv[u].w));
            *(short4v*)&Bs[row][col4] = pq.s;
        }
        __syncthreads();
        // MFMA: A[m=lane&15][k=qd*8+j], B[n=lane&15][k=qd*8+j]
#pragma unroll
        for (int ks = 0; ks < BK / 32; ks++) {
            const int kb = ks * 32 + qd * 8;
            short8 af[4], bfr[4];
#pragma unroll
            for (int ri = 0; ri < 4; ri++) af[ri] = *(const short8*)&As[RB + ri * 16 + n16][kb];
#pragma unroll
            for (int ci = 0; ci < 4; ci++) bfr[ci] = *(const short8*)&Bs[CB + ci * 16 + n16][kb];
#pragma unroll
            for (int ri = 0; ri < 4; ri++)
#pragma unroll
                for (int ci = 0; ci < 4; ci++)
                    acc[ri][ci] = __builtin_amdgcn_mfma_f32_16x16x32_bf16(
                        af[ri], bfr[ci], acc[ri][ci], 0, 0, 0);
        }
    }

    // reduce cw/qw partials: each u-slot's value lives on 16 lanes (same row)
#pragma unroll
    for (int u = 0; u < 8; u++) {
        float c = cwp[u], q = qwp[u];
#pragma unroll
        for (int off = 1; off < 16; off <<= 1) {
            c += __shfl_xor(c, off);
            q += __shfl_xor(q, off);
        }
        if (n16 == 0) {
            const int row = w * 32 + u * 4 + qd;
            cwL[row] = c; qwL[row] = q;
        }
    }
    __syncthreads();

    // Epilogue: v = acc + cw_i + qw_j; E = exp(v); spill fp16 E (col-major);
    // Z accumulated from the ROUNDED fp16 values for exact consistency.
    // C/D layout (16x16x32): col = lane&15, row = (lane>>4)*4 + reg
#pragma unroll
    for (int ci = 0; ci < 4; ci++) {
        const int col = CB + ci * 16 + n16;
        const float qwv = qwL[col];
        unsigned short* eCol = eh + ((size_t)(b * NTILE + bt) * NQ + col) * TM;
        float s = 0.f;
#pragma unroll
        for (int ri = 0; ri < 4; ri++) {
            const int rbase = RB + ri * 16 + qd * 4;
            float e0 = __expf(acc[ri][ci][0] + cwL[rbase + 0] + qwv);
            float e1 = __expf(acc[ri][ci][1] + cwL[rbase + 1] + qwv);
            float e2 = __expf(acc[ri][ci][2] + cwL[rbase + 2] + qwv);
            float e3 = __expf(acc[ri][ci][3] + cwL[rbase + 3] + qwv);
            half2v h01 = __builtin_amdgcn_cvt_pkrtz(e0, e1);
            half2v h23 = __builtin_amdgcn_cvt_pkrtz(e2, e3);
            s += (float)h01[0] + (float)h01[1] + (float)h23[0] + (float)h23[1];
            uint2 pk;
            pk.x = __builtin_bit_cast(unsigned, h01);
            pk.y = __builtin_bit_cast(unsigned, h23);
            *(uint2*)&eCol[rbase] = pk;
        }
        s += __shfl_xor(s, 16);
        s += __shfl_xor(s, 32);
        if (qd == 0) sL[wr][col] = s;
    }
    __syncthreads();
    if (tid < NQ)
        stats[(size_t)(b * NTILE + bt) * NQ + tid] = sL[0][tid] + sL[1][tid];
}

// ---------------------------------------------------------------------------
// K2 rb2: iz[j] = 1/sum_tiles Z; r_i = sum_j E_ij*iz_j (fp16 E, no expf);
// bpart[d] = sum_i r_i c_i[d] (float4/thread, split row-halves for ILP);
// plus this tile's 64-col slice of arow. Linear grid 512, XCD swizzle.
// ---------------------------------------------------------------------------
__global__ __launch_bounds__(256) void rb2(
    const float* __restrict__ ctx, const float* __restrict__ qry,
    const unsigned short* __restrict__ eh, const float* __restrict__ stats,
    float* __restrict__ bpart, float* __restrict__ arow)
{
    __shared__ __attribute__((aligned(16))) unsigned short eL[NQ * TM];
    __shared__ float izL[NQ];
    __shared__ float rpart[2][TM];
    __shared__ float rfin[TM];
    __shared__ float bH[2][DIMD];
    __shared__ float qL[4][64];

    const int tid  = threadIdx.x;
    const int bid  = blockIdx.x;
    const int orig = (bid & 7) * 64 + (bid >> 3);   // XCD-chunked swizzle
    const int b    = orig >> 3;
    const int bt   = orig & 7;
    const int i0   = bt * TM;

    if (tid < NQ) {
        float ssum = 0.f;
#pragma unroll
        for (int t8 = 0; t8 < NTILE; t8++)
            ssum += stats[(size_t)(b * NTILE + t8) * NQ + tid];
        izL[tid] = 1.0f / ssum;
    }
    const unsigned short* tileSrc = eh + (size_t)(b * NTILE + bt) * NQ * TM;
#pragma unroll
    for (int it = 0; it < 8; it++) {
        const int idx = (tid + it * 256) * 8;   // 8 ushorts = 16B per thread
        *(uint4*)&eL[idx] = *(const uint4*)&tileSrc[idx];
    }
    __syncthreads();

    const int i = tid & 127, jh = tid >> 7;
    float r = 0.f;
    for (int j2 = 0; j2 < 64; j2++) {
        const int j = jh * 64 + j2;
        __fp16 hv = __builtin_bit_cast(__fp16, eL[j * TM + i]);
        r += (float)hv * izL[j];
    }
    rpart[jh][i] = r;
    __syncthreads();
    if (tid < TM) rfin[tid] = rpart[0][tid] + rpart[1][tid];
    __syncthreads();

    // bpart: 128 threads per row-half, float4 per thread, unrolled for ILP
    const int dq = (tid & 127) * 4;
    const int rh = tid >> 7;
    f32x4 ba = {0.f, 0.f, 0.f, 0.f};
    const float* cb4 = ctx + ((size_t)b * NC + i0 + rh * 64) * DIMD + dq;
#pragma unroll 4
    for (int ii = 0; ii < 64; ii++) {
        float rv = rfin[rh * 64 + ii];
        f32x4 cv = *(const f32x4*)(cb4 + (size_t)ii * DIMD);
        ba += rv * cv;
    }
    *(f32x4*)&bH[rh][dq] = ba;
    __syncthreads();
    if (tid < 128) {
        const int d4 = tid * 4;
        f32x4 r0 = *(const f32x4*)&bH[0][d4];
        f32x4 r1 = *(const f32x4*)&bH[1][d4];
        f32x4 sum = r0 + r1;
        *(f32x4*)&bpart[(size_t)(b * NTILE + bt) * DIMD + d4] = sum;
    }

    // arow slice: this block computes arow[b][bt*64 .. bt*64+64)
    const int dcol = tid & 63, rgrp = tid >> 6;
    float qs = 0.f;
    const float* qb = qry + (size_t)b * NQ * DIMD + bt * 64 + dcol;
    for (int t = 0; t < 32; t++)
        qs += qb[(size_t)(t * 4 + rgrp) * DIMD];
    qL[rgrp][dcol] = qs;
    __syncthreads();
    if (tid < 64)
        arow[(size_t)b * DIMD + bt * 64 + tid] =
            qL[0][tid] + qL[1][tid] + qL[2][tid] + qL[3][tid];
}

// ---------------------------------------------------------------------------
// K3: reduce Brow partials + broadcast-write A and B (nontemporal: output is
// write-once, keep it out of L2). Grid (NB, 32), block 256.
// ---------------------------------------------------------------------------
__global__ void broadcast_out(const float* __restrict__ arow, const float* __restrict__ bpart,
                              float* __restrict__ out)
{
    const int b = blockIdx.x, ic = blockIdx.y;
    const int t = threadIdx.x;
    const int half = t >> 7;          // 0 -> A, 1 -> B (wave-uniform)
    const int l = t & 127;
    const int d0 = l * 4;
    f32x4 val;
    if (half == 0) {
        val = *(const f32x4*)&arow[(size_t)b * DIMD + d0];
    } else {
        val[0] = val[1] = val[2] = val[3] = 0.f;
        for (int t8 = 0; t8 < NTILE; t8++) {
            f32x4 v = *(const f32x4*)&bpart[(size_t)(b * NTILE + t8) * DIMD + d0];
            val[0] += v[0]; val[1] += v[1]; val[2] += v[2]; val[3] += v[3];
        }
    }
    size_t base = (size_t)half * ((size_t)NB * NC * DIMD)
                + ((size_t)b * NC + (size_t)ic * 32) * DIMD + d0;
    for (int i = 0; i < 32; i++)
        __builtin_nontemporal_store(val, (f32x4*)&out[base + (size_t)i * DIMD]);
}

extern "C" void kernel_launch(void* const* d_in, const int* in_sizes, int n_in,
                              void* d_out, int out_size, void* d_ws, size_t ws_size,
                              hipStream_t stream)
{
    const float* ctx = (const float*)d_in[0];  // (64,1024,512) f32
    const float* qry = (const float*)d_in[1];  // (64,128,512) f32
    const float* w0  = (const float*)d_in[2];  // (1536,) f32
    float* out = (float*)d_out;
    float* ws  = (float*)d_ws;

    float* stats = ws;                          // 64*8*128 = 65536 floats
    float* arow  = ws + 65536;                  // 64*512   = 32768
    float* bpart = ws + 98304;                  // 64*8*512 = 262144
    unsigned short* eh = (unsigned short*)(ws + 360448);  // 64*8*128*128 fp16 = 16.8 MB

    gemm_stats<<<dim3(NB * NTILE), 256, 0, stream>>>(ctx, qry, w0, stats, eh);
    rb2<<<dim3(NB * NTILE), 256, 0, stream>>>(ctx, qry, eh, stats, bpart, arow);
    broadcast_out<<<dim3(NB, 32), 256, 0, stream>>>(arow, bpart, out);
}